// Round 3
// baseline (4917.053 us; speedup 1.0000x reference)
//
#include <hip/hip_runtime.h>
#include <hip/hip_bf16.h>

typedef __hip_bfloat16 bf16;

constexpr int kHW = 96 * 96;   // 9216

__device__ __forceinline__ float b2f(bf16 x){ return __bfloat162float(x); }
__device__ __forceinline__ bf16  f2b(float x){ return __float2bfloat16(x); }

// bilinear 2x upsample sample of high (b,512,48,48) fp32 at output (x=W,y=H,c)
__device__ __forceinline__ float hf_at(const float* __restrict__ hi, int b, int x, int y, int c){
  int j = y >> 1, i = x >> 1;
  int j0, j1, i0, i1; float wy0, wy1, wx0, wx1;
  if ((y & 1) == 0){ j0 = j - 1; if (j0 < 0) j0 = 0; j1 = j; wy0 = 0.25f; wy1 = 0.75f; }
  else             { j0 = j; j1 = j + 1; if (j1 > 47) j1 = 47; wy0 = 0.75f; wy1 = 0.25f; }
  if ((x & 1) == 0){ i0 = i - 1; if (i0 < 0) i0 = 0; i1 = i; wx0 = 0.25f; wx1 = 0.75f; }
  else             { i0 = i; i1 = i + 1; if (i1 > 47) i1 = 47; wx0 = 0.75f; wx1 = 0.25f; }
  const float* p = hi + ((size_t)b*512 + c)*2304;
  return wy0*(wx0*p[j0*48 + i0] + wx1*p[j0*48 + i1])
       + wy1*(wx0*p[j1*48 + i0] + wx1*p[j1*48 + i1]);
}

// zero s1/s2 (1024 contiguous floats)
__global__ void k_zero(float* __restrict__ p){
  int i = blockIdx.x*256 + threadIdx.x;
  if (i < 1024) p[i] = 0.0f;
}

// fold q path: qq_w[o,c] = sum_k q_w[o,k]*conv1_w[k,c]  (32x512, fp32)
__global__ void k_qqw(const float* __restrict__ q_w, const float* __restrict__ c1_w,
                      float* __restrict__ qq_w){
  int gid = blockIdx.x*256 + threadIdx.x;      // 16384
  int o = gid >> 9, c = gid & 511;
  float acc = 0.f;
  for (int k = 0; k < 256; k++) acc += q_w[o*256 + k] * c1_w[k*512 + c];
  qq_w[gid] = acc;
}
__global__ void k_qqb(const float* __restrict__ q_w, const float* __restrict__ c1_b,
                      const float* __restrict__ q_b, float* __restrict__ qq_b){
  int o = threadIdx.x; if (o >= 32) return;
  float acc = q_b[o];
  for (int k = 0; k < 256; k++) acc += q_w[o*256 + k] * c1_b[k];
  qq_b[o] = acc;
}

// conv2 on upsampled hf (fused): vf_t[b,n,o] = sum_c hf[b,n,c]*c2w[o,c] + c2b[o]
// n = x*96 + y ; grid (144, 4, 8), 64n x 64o tile
__global__ __launch_bounds__(256) void k_conv2(const float* __restrict__ hi,
                                               const float* __restrict__ Wt,
                                               const float* __restrict__ bias,
                                               bf16* __restrict__ out){
  int b = blockIdx.z, n0 = blockIdx.x*64, o0 = blockIdx.y*64, t = threadIdx.x;
  int tn = t % 16, to = t / 16;
  __shared__ __align__(16) float As[32][68];
  __shared__ __align__(16) float Ws[32][68];
  float acc[4][4] = {};
  for (int c0 = 0; c0 < 512; c0 += 32){
    for (int e = t; e < 2048; e += 256){
      int nl = e >> 5, kk = e & 31;
      int n = n0 + nl, x = n / 96, y = n % 96;
      As[kk][nl] = hf_at(hi, b, x, y, c0 + kk);
    }
    for (int e = t; e < 2048; e += 256){
      int ol = e >> 5, kk = e & 31;
      Ws[kk][ol] = Wt[(size_t)(o0+ol)*512 + c0 + kk];
    }
    __syncthreads();
    #pragma unroll
    for (int kk = 0; kk < 32; kk++){
      float4 av = *(const float4*)&As[kk][tn*4];
      float4 wv = *(const float4*)&Ws[kk][to*4];
      float a_[4] = {av.x, av.y, av.z, av.w};
      float w_[4] = {wv.x, wv.y, wv.z, wv.w};
      #pragma unroll
      for (int i = 0; i < 4; i++)
        #pragma unroll
        for (int jj = 0; jj < 4; jj++) acc[i][jj] += a_[i]*w_[jj];
    }
    __syncthreads();
  }
  #pragma unroll
  for (int i = 0; i < 4; i++){
    size_t base = ((size_t)b*kHW + n0 + tn*4 + i)*256 + o0 + to*4;
    #pragma unroll
    for (int jj = 0; jj < 4; jj++) out[base + jj] = f2b(acc[i][jj] + bias[o0 + to*4 + jj]);
  }
}

// q directly from low (NCHW fp32): q_t[b,x,h,32] bf16 ; grid (96 h, 8 b)
__global__ __launch_bounds__(256) void k_qlow(const float* __restrict__ low,
                                              const float* __restrict__ qq_w,
                                              const float* __restrict__ qq_b,
                                              bf16* __restrict__ q_t){
  int h = blockIdx.x, b = blockIdx.y, t = threadIdx.x;
  int tw = t % 32, to = t / 32;
  __shared__ __align__(16) float Al[64][98];
  __shared__ __align__(16) float Wl[64][36];
  float acc[3][4] = {};
  for (int c0 = 0; c0 < 512; c0 += 64){
    for (int e = t; e < 64*96; e += 256){
      int cl = e / 96, x = e % 96;
      Al[cl][x] = low[(((size_t)b*512 + c0 + cl)*96 + h)*96 + x];
    }
    for (int e = t; e < 32*64; e += 256){
      int o = e >> 6, k = e & 63;
      Wl[k][o] = qq_w[(size_t)o*512 + c0 + k];
    }
    __syncthreads();
    #pragma unroll 4
    for (int k = 0; k < 64; k++){
      float a_[3];
      #pragma unroll
      for (int i = 0; i < 3; i++) a_[i] = Al[k][tw*3 + i];
      float4 wv = *(const float4*)&Wl[k][to*4];
      float w_[4] = {wv.x, wv.y, wv.z, wv.w};
      #pragma unroll
      for (int i = 0; i < 3; i++)
        #pragma unroll
        for (int jj = 0; jj < 4; jj++) acc[i][jj] += a_[i]*w_[jj];
    }
    __syncthreads();
  }
  #pragma unroll
  for (int i = 0; i < 3; i++){
    int x = tw*3 + i;
    size_t base = (((size_t)b*96 + x)*96 + h)*32 + to*4;
    #pragma unroll
    for (int jj = 0; jj < 4; jj++) q_t[base + jj] = f2b(acc[i][jj] + qq_b[to*4 + jj]);
  }
}

// bf16-A (n,c) @ fp32-W (o,c)^T + fp32 bias -> bf16 ; A (b,9216,Cin), out (b,9216,O)
template<int BN, int OT>
__global__ __launch_bounds__(256) void k_gemm_bb(const bf16* __restrict__ A,
                                                 const float* __restrict__ Wt,
                                                 const float* __restrict__ bias,
                                                 bf16* __restrict__ out,
                                                 int Cin, int O){
  constexpr int TN = BN/4;
  int b = blockIdx.z, n0 = blockIdx.x*BN, o0 = blockIdx.y*OT, t = threadIdx.x;
  int tn = t % TN, to = t / TN;
  __shared__ __align__(16) float As[32][BN+4];
  __shared__ __align__(16) float Ws[32][OT+4];
  float acc[4][4] = {};
  const bf16* Ab = A + (size_t)b*kHW*Cin;
  for (int c0 = 0; c0 < Cin; c0 += 32){
    for (int e = t; e < BN*32; e += 256){
      int nl = e >> 5, kk = e & 31;
      As[kk][nl] = b2f(Ab[(size_t)(n0+nl)*Cin + c0 + kk]);
    }
    for (int e = t; e < OT*32; e += 256){
      int ol = e >> 5, kk = e & 31;
      Ws[kk][ol] = Wt[(size_t)(o0+ol)*Cin + c0 + kk];
    }
    __syncthreads();
    #pragma unroll
    for (int kk = 0; kk < 32; kk++){
      float4 av = *(const float4*)&As[kk][tn*4];
      float4 wv = *(const float4*)&Ws[kk][to*4];
      float a_[4] = {av.x, av.y, av.z, av.w};
      float w_[4] = {wv.x, wv.y, wv.z, wv.w};
      #pragma unroll
      for (int i = 0; i < 4; i++)
        #pragma unroll
        for (int jj = 0; jj < 4; jj++) acc[i][jj] += a_[i]*w_[jj];
    }
    __syncthreads();
  }
  #pragma unroll
  for (int i = 0; i < 4; i++){
    size_t base = ((size_t)b*kHW + n0 + tn*4 + i)*(size_t)O + o0 + to*4;
    #pragma unroll
    for (int jj = 0; jj < 4; jj++) out[base + jj] = f2b(acc[i][jj] + bias[o0 + to*4 + jj]);
  }
}

// eH: att[b,h,w,j] = sum_c q_t[b,w,h,c]*k_t[b,w,j,c]  (-1e9 if j==h); grid (96 w, 8 b)
__global__ __launch_bounds__(256) void k_eH(const bf16* __restrict__ q_t,
                                            const bf16* __restrict__ k_t,
                                            bf16* __restrict__ att){
  int w = blockIdx.x, b = blockIdx.y, t = threadIdx.x;
  __shared__ float Qs[96][33];
  __shared__ float Ks[96][33];
  const bf16* Qp = q_t + (((size_t)b*96 + w)*96)*32;
  const bf16* Kp = k_t + (((size_t)b*96 + w)*96)*32;
  for (int e = t; e < 3072; e += 256){ Qs[e>>5][e&31] = b2f(Qp[e]); Ks[e>>5][e&31] = b2f(Kp[e]); }
  __syncthreads();
  int tj = t % 16, th = t / 16;
  float acc[6][6] = {};
  #pragma unroll 4
  for (int c = 0; c < 32; c++){
    float qa[6], kb[6];
    #pragma unroll
    for (int i = 0; i < 6; i++) qa[i] = Qs[th*6 + i][c];
    #pragma unroll
    for (int jj = 0; jj < 6; jj++) kb[jj] = Ks[tj*6 + jj][c];
    #pragma unroll
    for (int i = 0; i < 6; i++)
      #pragma unroll
      for (int jj = 0; jj < 6; jj++) acc[i][jj] += qa[i]*kb[jj];
  }
  #pragma unroll
  for (int i = 0; i < 6; i++){
    int h = th*6 + i;
    size_t base = (((size_t)b*96 + h)*96 + w)*192;
    #pragma unroll
    for (int jj = 0; jj < 6; jj++){
      int jg = tj*6 + jj;
      float e = acc[i][jj];
      if (jg == h) e += -1000000000.0f;
      att[base + jg] = f2b(e);
    }
  }
}

// eW: att[b,h,w,96+j] = sum_c q_t[b,w,h,c]*k_t[b,j,h,c]; grid (96 h, 8 b)
__global__ __launch_bounds__(256) void k_eW(const bf16* __restrict__ q_t,
                                            const bf16* __restrict__ k_t,
                                            bf16* __restrict__ att){
  int h = blockIdx.x, b = blockIdx.y, t = threadIdx.x;
  __shared__ float Qs[96][33];
  __shared__ float Ks[96][33];
  for (int e = t; e < 3072; e += 256){
    int wl = e >> 5, c = e & 31;
    size_t idx = (((size_t)b*96 + wl)*96 + h)*32 + c;
    Qs[wl][c] = b2f(q_t[idx]);
    Ks[wl][c] = b2f(k_t[idx]);
  }
  __syncthreads();
  int tj = t % 16, tw = t / 16;
  float acc[6][6] = {};
  #pragma unroll 4
  for (int c = 0; c < 32; c++){
    float qa[6], kb[6];
    #pragma unroll
    for (int i = 0; i < 6; i++) qa[i] = Qs[tw*6 + i][c];
    #pragma unroll
    for (int jj = 0; jj < 6; jj++) kb[jj] = Ks[tj*6 + jj][c];
    #pragma unroll
    for (int i = 0; i < 6; i++)
      #pragma unroll
      for (int jj = 0; jj < 6; jj++) acc[i][jj] += qa[i]*kb[jj];
  }
  #pragma unroll
  for (int i = 0; i < 6; i++){
    int wl = tw*6 + i;
    size_t base = (((size_t)b*96 + h)*96 + wl)*192 + 96;
    #pragma unroll
    for (int jj = 0; jj < 6; jj++) att[base + tj*6 + jj] = f2b(acc[i][jj]);
  }
}

// softmax over 192, one wave per row; grid 18432
__global__ __launch_bounds__(256) void k_softmax(bf16* __restrict__ att){
  int t = threadIdx.x;
  int row = blockIdx.x*4 + (t >> 6);
  int lane = t & 63;
  size_t base = (size_t)row * 192;
  float x0 = b2f(att[base + lane]);
  float x1 = b2f(att[base + 64 + lane]);
  float x2 = b2f(att[base + 128 + lane]);
  float m = fmaxf(x0, fmaxf(x1, x2));
  #pragma unroll
  for (int off = 32; off; off >>= 1) m = fmaxf(m, __shfl_xor(m, off));
  float e0 = __expf(x0 - m), e1 = __expf(x1 - m), e2 = __expf(x2 - m);
  float s = e0 + e1 + e2;
  #pragma unroll
  for (int off = 32; off; off >>= 1) s += __shfl_xor(s, off);
  float inv = 1.0f / s;
  att[base + lane]       = f2b(e0 * inv);
  att[base + 64 + lane]  = f2b(e1 * inv);
  att[base + 128 + lane] = f2b(e2 * inv);
}

// outH: accb[b,w,h,c] = sum_j att[b,h,w,j]*v_t[b,w,j,c]; grid (96 w, 8 b, 2)
__global__ __launch_bounds__(256) void k_outH(const bf16* __restrict__ att,
                                              const bf16* __restrict__ v_t,
                                              bf16* __restrict__ accb){
  int w = blockIdx.x, b = blockIdx.y, c0 = blockIdx.z * 128, t = threadIdx.x;
  int tc = t % 16, th = t / 16;
  __shared__ float As[96][33];
  __shared__ __align__(16) float Vs[32][128];
  float acc[6][8] = {};
  for (int j0 = 0; j0 < 96; j0 += 32){
    for (int e = t; e < 3072; e += 256){
      int hh = e >> 5, jj = e & 31;
      As[hh][jj] = b2f(att[(((size_t)b*96 + hh)*96 + w)*192 + j0 + jj]);
    }
    for (int e = t; e < 4096; e += 256){
      int jj = e >> 7, c = e & 127;
      Vs[jj][c] = b2f(v_t[(((size_t)b*96 + w)*96 + j0 + jj)*256 + c0 + c]);
    }
    __syncthreads();
    #pragma unroll 2
    for (int jj = 0; jj < 32; jj++){
      float a_[6];
      #pragma unroll
      for (int i = 0; i < 6; i++) a_[i] = As[th*6 + i][jj];
      float4 v0 = *(const float4*)&Vs[jj][tc*4];
      float4 v1 = *(const float4*)&Vs[jj][64 + tc*4];
      #pragma unroll
      for (int i = 0; i < 6; i++){
        acc[i][0] += a_[i]*v0.x; acc[i][1] += a_[i]*v0.y;
        acc[i][2] += a_[i]*v0.z; acc[i][3] += a_[i]*v0.w;
        acc[i][4] += a_[i]*v1.x; acc[i][5] += a_[i]*v1.y;
        acc[i][6] += a_[i]*v1.z; acc[i][7] += a_[i]*v1.w;
      }
    }
    __syncthreads();
  }
  #pragma unroll
  for (int i = 0; i < 6; i++){
    int h = th*6 + i;
    size_t base = (((size_t)b*96 + w)*96 + h)*256 + c0;
    #pragma unroll
    for (int jj = 0; jj < 4; jj++) accb[base + tc*4 + jj]      = f2b(acc[i][jj]);
    #pragma unroll
    for (int jj = 0; jj < 4; jj++) accb[base + 64 + tc*4 + jj] = f2b(acc[i][4 + jj]);
  }
}

// outW + residual: vf_t[b,w,h,c] += g*(accb + sum_j att[...,96+j]*v_t[b,j,h,c]); grid (96 h, 8 b, 2)
__global__ __launch_bounds__(256) void k_outW(const bf16* __restrict__ att,
                                              const bf16* __restrict__ v_t,
                                              const bf16* __restrict__ accb,
                                              const float* __restrict__ gamma_p,
                                              bf16* __restrict__ vf_t){
  int h = blockIdx.x, b = blockIdx.y, c0 = blockIdx.z * 128, t = threadIdx.x;
  int tc = t % 16, tw = t / 16;
  __shared__ float As[96][33];
  __shared__ __align__(16) float Vs[32][128];
  float acc[6][8] = {};
  for (int j0 = 0; j0 < 96; j0 += 32){
    for (int e = t; e < 3072; e += 256){
      int wl = e >> 5, jj = e & 31;
      As[wl][jj] = b2f(att[(((size_t)b*96 + h)*96 + wl)*192 + 96 + j0 + jj]);
    }
    for (int e = t; e < 4096; e += 256){
      int jj = e >> 7, c = e & 127;
      Vs[jj][c] = b2f(v_t[(((size_t)b*96 + j0 + jj)*96 + h)*256 + c0 + c]);
    }
    __syncthreads();
    #pragma unroll 2
    for (int jj = 0; jj < 32; jj++){
      float a_[6];
      #pragma unroll
      for (int i = 0; i < 6; i++) a_[i] = As[tw*6 + i][jj];
      float4 v0 = *(const float4*)&Vs[jj][tc*4];
      float4 v1 = *(const float4*)&Vs[jj][64 + tc*4];
      #pragma unroll
      for (int i = 0; i < 6; i++){
        acc[i][0] += a_[i]*v0.x; acc[i][1] += a_[i]*v0.y;
        acc[i][2] += a_[i]*v0.z; acc[i][3] += a_[i]*v0.w;
        acc[i][4] += a_[i]*v1.x; acc[i][5] += a_[i]*v1.y;
        acc[i][6] += a_[i]*v1.z; acc[i][7] += a_[i]*v1.w;
      }
    }
    __syncthreads();
  }
  float g = gamma_p[0];
  #pragma unroll
  for (int i = 0; i < 6; i++){
    int wl = tw*6 + i;
    size_t base = (((size_t)b*96 + wl)*96 + h)*256 + c0;
    #pragma unroll
    for (int jj = 0; jj < 8; jj++){
      size_t idx = base + (jj >> 2)*64 + tc*4 + (jj & 3);
      vf_t[idx] = f2b(b2f(vf_t[idx]) + g*(acc[i][jj] + b2f(accb[idx])));
    }
  }
}

// bottleneck: bt[b,n,co] = sum_{c<256} vf*bw + sum_{c<512} hf(recomputed)*bw ; + stats
__global__ __launch_bounds__(256) void k_bneck(const bf16* __restrict__ vf_t,
                                               const float* __restrict__ hi,
                                               const float* __restrict__ bw,
                                               bf16* __restrict__ bt,
                                               float* __restrict__ s1,
                                               float* __restrict__ s2){
  int b = blockIdx.z, n0 = blockIdx.x*64, o0 = blockIdx.y*64, t = threadIdx.x;
  int tn = t % 16, to = t / 16;
  __shared__ __align__(16) float As[32][68];
  __shared__ __align__(16) float Ws[32][68];
  float acc[4][4] = {};
  for (int c0 = 0; c0 < 768; c0 += 32){
    if (c0 < 256){
      const bf16* Ap = vf_t + (size_t)b*kHW*256;
      for (int e = t; e < 2048; e += 256){
        int nl = e >> 5, kk = e & 31;
        As[kk][nl] = b2f(Ap[(size_t)(n0+nl)*256 + c0 + kk]);
      }
    } else {
      for (int e = t; e < 2048; e += 256){
        int nl = e >> 5, kk = e & 31;
        int n = n0 + nl, x = n / 96, y = n % 96;
        As[kk][nl] = hf_at(hi, b, x, y, c0 - 256 + kk);
      }
    }
    for (int e = t; e < 2048; e += 256){
      int ol = e >> 5, kk = e & 31;
      Ws[kk][ol] = bw[(size_t)(o0+ol)*768 + c0 + kk];
    }
    __syncthreads();
    #pragma unroll
    for (int kk = 0; kk < 32; kk++){
      float4 av = *(const float4*)&As[kk][tn*4];
      float4 wv = *(const float4*)&Ws[kk][to*4];
      float a_[4] = {av.x, av.y, av.z, av.w};
      float w_[4] = {wv.x, wv.y, wv.z, wv.w};
      #pragma unroll
      for (int i = 0; i < 4; i++)
        #pragma unroll
        for (int jj = 0; jj < 4; jj++) acc[i][jj] += a_[i]*w_[jj];
    }
    __syncthreads();
  }
  __shared__ float red1[64];
  __shared__ float red2[64];
  if (t < 64){ red1[t] = 0.f; red2[t] = 0.f; }
  __syncthreads();
  #pragma unroll
  for (int i = 0; i < 4; i++){
    size_t base = ((size_t)b*kHW + n0 + tn*4 + i)*512 + o0 + to*4;
    #pragma unroll
    for (int jj = 0; jj < 4; jj++) bt[base + jj] = f2b(acc[i][jj]);
  }
  #pragma unroll
  for (int jj = 0; jj < 4; jj++){
    float p1 = 0.f, p2 = 0.f;
    #pragma unroll
    for (int i = 0; i < 4; i++){ p1 += acc[i][jj]; p2 += acc[i][jj]*acc[i][jj]; }
    atomicAdd(&red1[to*4 + jj], p1);
    atomicAdd(&red2[to*4 + jj], p2);
  }
  __syncthreads();
  if (t < 64){
    atomicAdd(&s1[o0 + t], red1[t]);
    atomicAdd(&s2[o0 + t], red2[t]);
  }
}

__global__ void k_bnprep(const float* __restrict__ s1, const float* __restrict__ s2,
                         const float* __restrict__ sc, const float* __restrict__ bi,
                         float2* __restrict__ ab){
  int co = blockIdx.x*256 + threadIdx.x;
  if (co >= 512) return;
  const float N = 73728.0f;
  float mean = s1[co] / N;
  float var  = s2[co] / N - mean*mean;
  if (var < 0.f) var = 0.f;
  float a = rsqrtf(var + 1e-5f) * sc[co];
  ab[co] = make_float2(a, bi[co] - mean*a);
}

// BN + relu + transpose (b,w,h,co) -> (b,co,h,w) fp32; grid (3, 96, 8)
__global__ __launch_bounds__(256) void k_bnout(const bf16* __restrict__ bt,
                                               const float2* __restrict__ ab,
                                               float* __restrict__ out){
  int w0 = blockIdx.x*32, h = blockIdx.y, b = blockIdx.z, t = threadIdx.x;
  __shared__ float Tl[32][33];
  for (int co0 = 0; co0 < 512; co0 += 32){
    for (int e = t; e < 1024; e += 256){
      int wl = e >> 5, co = e & 31;
      Tl[wl][co] = b2f(bt[(((size_t)b*96 + w0 + wl)*96 + h)*512 + co0 + co]);
    }
    __syncthreads();
    for (int e = t; e < 1024; e += 256){
      int co = e >> 5, wl = e & 31;
      float2 s = ab[co0 + co];
      float v = fmaxf(Tl[wl][co]*s.x + s.y, 0.0f);
      out[(((size_t)b*512 + co0 + co)*96 + h)*96 + w0 + wl] = v;
    }
    __syncthreads();
  }
}

// ---------------------------------------------------------------------------
extern "C" void kernel_launch(void* const* d_in, const int* in_sizes, int n_in,
                              void* d_out, int out_size, void* d_ws, size_t ws_size,
                              hipStream_t stream){
  (void)in_sizes; (void)n_in; (void)out_size; (void)ws_size;
  const float* low   = (const float*)d_in[0];
  const float* high  = (const float*)d_in[1];
  const float* c1w   = (const float*)d_in[2];
  const float* c1b   = (const float*)d_in[3];
  const float* c2w   = (const float*)d_in[4];
  const float* c2b   = (const float*)d_in[5];
  const float* qw    = (const float*)d_in[6];
  const float* qb    = (const float*)d_in[7];
  const float* kw    = (const float*)d_in[8];
  const float* kb    = (const float*)d_in[9];
  const float* vw    = (const float*)d_in[10];
  const float* vb    = (const float*)d_in[11];
  const float* gamma = (const float*)d_in[12];
  const float* bw    = (const float*)d_in[13];
  const float* bns   = (const float*)d_in[14];
  const float* bnb   = (const float*)d_in[15];
  float* out = (float*)d_out;

  char* wsb = (char*)d_ws;
  // workspace layout — total 146,350,592 bytes (~139.6 MB)
  bf16*   vf_t = (bf16*) (wsb + 0);            // 37,748,736
  bf16*   q_t  = (bf16*) (wsb + 37748736);     //  4,718,592
  float*  qq_w = (float*)(wsb + 42467328);     //     65,536
  float*  qq_b = (float*)(wsb + 42532864);     //        128
  float*  s1   = (float*)(wsb + 42532992);     //      2,048
  float*  s2   = (float*)(wsb + 42535040);     //      2,048
  float2* ab   = (float2*)(wsb + 42537088);    //      4,096
  bf16*   v_t  = (bf16*) (wsb + 42541568);     // 37,748,736
  bf16*   att  = (bf16*) (wsb + 80290304);     // 28,311,552
  bf16*   accb = (bf16*) (wsb + 108601856);    // 37,748,736 -> ends 146,350,592
  bf16*   k_t  = (bf16*) (wsb + 108601856);    //  4,718,592 (aliases accb head; dead before accb written)
  bf16*   bt   = (bf16*) (wsb + 42541568);     // 75,497,472 (aliases v_t/att/accb-head; all dead at bneck)

  k_zero<<<4, 256, 0, stream>>>(s1);                    // zeros s1+s2 (contiguous 1024 floats)
  k_qqw<<<64, 256, 0, stream>>>(qw, c1w, qq_w);
  k_qqb<<<1, 64, 0, stream>>>(qw, c1b, qb, qq_b);
  k_conv2<<<dim3(144, 4, 8), 256, 0, stream>>>(high, c2w, c2b, vf_t);
  k_qlow<<<dim3(96, 8), 256, 0, stream>>>(low, qq_w, qq_b, q_t);

  for (int r = 0; r < 2; r++){
    k_gemm_bb<128, 32><<<dim3(72, 1, 8), 256, 0, stream>>>(vf_t, kw, kb, k_t, 256, 32);
    k_gemm_bb<64, 64><<<dim3(144, 4, 8), 256, 0, stream>>>(vf_t, vw, vb, v_t, 256, 256);
    k_eH<<<dim3(96, 8), 256, 0, stream>>>(q_t, k_t, att);
    k_eW<<<dim3(96, 8), 256, 0, stream>>>(q_t, k_t, att);
    k_softmax<<<18432, 256, 0, stream>>>(att);
    k_outH<<<dim3(96, 8, 2), 256, 0, stream>>>(att, v_t, accb);
    k_outW<<<dim3(96, 8, 2), 256, 0, stream>>>(att, v_t, accb, gamma, vf_t);
  }

  k_bneck<<<dim3(144, 8, 8), 256, 0, stream>>>(vf_t, high, bw, bt, s1, s2);
  k_bnprep<<<2, 256, 0, stream>>>(s1, s2, bns, bnb, ab);
  k_bnout<<<dim3(3, 96, 8), 256, 0, stream>>>(bt, ab, out);
}

// Round 4
// 1201.711 us; speedup vs baseline: 4.0917x; 4.0917x over previous
//
#include <hip/hip_runtime.h>
#include <hip/hip_bf16.h>

typedef __hip_bfloat16 bf16;
typedef __attribute__((ext_vector_type(8))) short short8;
typedef __attribute__((ext_vector_type(4))) float f32x4;

constexpr int kHW = 96 * 96;   // 9216

__device__ __forceinline__ float b2f(bf16 x){ return __bfloat162float(x); }
__device__ __forceinline__ bf16  f2b(float x){ return __float2bfloat16(x); }

// ---------------------------------------------------------------------------
// zero s1/s2 (1024 contiguous floats)
__global__ void k_zero(float* __restrict__ p){
  int i = blockIdx.x*256 + threadIdx.x;
  if (i < 1024) p[i] = 0.0f;
}

// fp32 -> bf16 weight conversion
__global__ void k_cvt(const float* __restrict__ s, bf16* __restrict__ d, int n){
  int i = blockIdx.x*256 + threadIdx.x;
  if (i < n) d[i] = f2b(s[i]);
}

// ---------------------------------------------------------------------------
// bilinear 2x upsample: high (b,512,48,48) fp32 -> hf_t (b, x96*96+y, c512) bf16
// grid (y=96, b=8), 256 thr
__global__ __launch_bounds__(256) void k_upsample(const float* __restrict__ hi,
                                                  bf16* __restrict__ hf_t){
  int y = blockIdx.x, b = blockIdx.y, t = threadIdx.x;
  int j = y >> 1;
  int j0, j1; float wy0, wy1;
  if ((y & 1) == 0){ j0 = j - 1; if (j0 < 0) j0 = 0; j1 = j; wy0 = 0.25f; wy1 = 0.75f; }
  else             { j0 = j; j1 = j + 1; if (j1 > 47) j1 = 47; wy0 = 0.75f; wy1 = 0.25f; }
  __shared__ __align__(16) float sm[2][128][49];
  for (int c0 = 0; c0 < 512; c0 += 128){
    for (int e = t; e < 2*128*48; e += 256){
      int cl = e / 96; int r = e % 96; int jj = r / 48; int i = r % 48;
      int row = jj ? j1 : j0;
      sm[jj][cl][i] = hi[(((size_t)b*512 + c0 + cl)*48 + row)*48 + i];
    }
    __syncthreads();
    for (int e = t; e < 96*128; e += 256){
      int x = e >> 7; int cl = e & 127;
      int i = x >> 1; int i0, i1; float wx0, wx1;
      if ((x & 1) == 0){ i0 = i - 1; if (i0 < 0) i0 = 0; i1 = i; wx0 = 0.25f; wx1 = 0.75f; }
      else             { i0 = i; i1 = i + 1; if (i1 > 47) i1 = 47; wx0 = 0.75f; wx1 = 0.25f; }
      float v = wy0*(wx0*sm[0][cl][i0] + wx1*sm[0][cl][i1])
              + wy1*(wx0*sm[1][cl][i0] + wx1*sm[1][cl][i1]);
      hf_t[(((size_t)b*96 + x)*96 + y)*512 + c0 + cl] = f2b(v);
    }
    __syncthreads();
  }
}

// ---------------------------------------------------------------------------
// fold q path: qq_w[o,c] = sum_k q_w[o,k]*conv1_w[k,c]  (32x512, fp32)
__global__ void k_qqw(const float* __restrict__ q_w, const float* __restrict__ c1_w,
                      float* __restrict__ qq_w){
  int gid = blockIdx.x*256 + threadIdx.x;      // 16384
  int o = gid >> 9, c = gid & 511;
  float acc = 0.f;
  for (int k = 0; k < 256; k++) acc += q_w[o*256 + k] * c1_w[k*512 + c];
  qq_w[gid] = acc;
}
__global__ void k_qqb(const float* __restrict__ q_w, const float* __restrict__ c1_b,
                      const float* __restrict__ q_b, float* __restrict__ qq_b){
  int o = threadIdx.x; if (o >= 32) return;
  float acc = q_b[o];
  for (int k = 0; k < 256; k++) acc += q_w[o*256 + k] * c1_b[k];
  qq_b[o] = acc;
}

// ---------------------------------------------------------------------------
// MFMA GEMM: out[b,n,o] = sum_k A[b,n,k]*Wb[o,k] (+bias[o])
// A bf16 (b,9216,K) row-major; Wb bf16 (O,K); out bf16 (b,9216,O)
// 128x128 block tile, 4 waves of 64x64 (4x4 16x16x32 mfma tiles), BK=32
__global__ __launch_bounds__(256) void k_mfma_gemm(const bf16* __restrict__ A,
                                                   const bf16* __restrict__ Wb,
                                                   const float* __restrict__ bias,
                                                   bf16* __restrict__ out,
                                                   int K, int O){
  int b = blockIdx.z, n0 = blockIdx.x*128, o0 = blockIdx.y*128;
  int t = threadIdx.x, lane = t & 63, wv = t >> 6;
  int m_off = (wv & 1)*64, o_off = (wv >> 1)*64;
  int lm = lane & 15, lk = lane >> 4;
  __shared__ __align__(16) bf16 As[128*40];
  __shared__ __align__(16) bf16 Ws[128*40];
  f32x4 acc[4][4] = {};
  const bf16* Ab = A + (size_t)b*kHW*K;
  for (int c0 = 0; c0 < K; c0 += 32){
    for (int e = t; e < 512; e += 256){
      int nl = e >> 2, p = e & 3;
      *(uint4*)&As[nl*40 + p*8] = *(const uint4*)&Ab[(size_t)(n0+nl)*K + c0 + p*8];
    }
    for (int e = t; e < 512; e += 256){
      int ol = e >> 2, p = e & 3;
      *(uint4*)&Ws[ol*40 + p*8] = *(const uint4*)&Wb[(size_t)(o0+ol)*K + c0 + p*8];
    }
    __syncthreads();
    short8 af[4], bfr[4];
    #pragma unroll
    for (int i = 0; i < 4; i++){
      af[i]  = *(const short8*)&As[(m_off + i*16 + lm)*40 + lk*8];
      bfr[i] = *(const short8*)&Ws[(o_off + i*16 + lm)*40 + lk*8];
    }
    #pragma unroll
    for (int i = 0; i < 4; i++)
      #pragma unroll
      for (int j = 0; j < 4; j++)
        acc[i][j] = __builtin_amdgcn_mfma_f32_16x16x32_bf16(af[i], bfr[j], acc[i][j], 0, 0, 0);
    __syncthreads();
  }
  #pragma unroll
  for (int j = 0; j < 4; j++){
    int oc = o0 + o_off + j*16 + lm;
    float bs = bias ? bias[oc] : 0.0f;
    #pragma unroll
    for (int i = 0; i < 4; i++){
      int rbase = n0 + m_off + i*16 + lk*4;
      #pragma unroll
      for (int r = 0; r < 4; r++)
        out[((size_t)b*kHW + rbase + r)*(size_t)O + oc] = f2b(acc[i][j][r] + bs);
    }
  }
}

// bottleneck MFMA: K=768 split A-source (k<256: vf_t stride 256; k>=256: hf_t stride 512)
__global__ __launch_bounds__(256) void k_bneck_mfma(const bf16* __restrict__ vf,
                                                    const bf16* __restrict__ hf,
                                                    const bf16* __restrict__ Wb,
                                                    bf16* __restrict__ out){
  int b = blockIdx.z, n0 = blockIdx.x*128, o0 = blockIdx.y*128;
  int t = threadIdx.x, lane = t & 63, wv = t >> 6;
  int m_off = (wv & 1)*64, o_off = (wv >> 1)*64;
  int lm = lane & 15, lk = lane >> 4;
  __shared__ __align__(16) bf16 As[128*40];
  __shared__ __align__(16) bf16 Ws[128*40];
  f32x4 acc[4][4] = {};
  for (int c0 = 0; c0 < 768; c0 += 32){
    const bf16* src; int strd, cc;
    if (c0 < 256){ src = vf + (size_t)b*kHW*256; strd = 256; cc = c0; }
    else         { src = hf + (size_t)b*kHW*512; strd = 512; cc = c0 - 256; }
    for (int e = t; e < 512; e += 256){
      int nl = e >> 2, p = e & 3;
      *(uint4*)&As[nl*40 + p*8] = *(const uint4*)&src[(size_t)(n0+nl)*strd + cc + p*8];
    }
    for (int e = t; e < 512; e += 256){
      int ol = e >> 2, p = e & 3;
      *(uint4*)&Ws[ol*40 + p*8] = *(const uint4*)&Wb[(size_t)(o0+ol)*768 + c0 + p*8];
    }
    __syncthreads();
    short8 af[4], bfr[4];
    #pragma unroll
    for (int i = 0; i < 4; i++){
      af[i]  = *(const short8*)&As[(m_off + i*16 + lm)*40 + lk*8];
      bfr[i] = *(const short8*)&Ws[(o_off + i*16 + lm)*40 + lk*8];
    }
    #pragma unroll
    for (int i = 0; i < 4; i++)
      #pragma unroll
      for (int j = 0; j < 4; j++)
        acc[i][j] = __builtin_amdgcn_mfma_f32_16x16x32_bf16(af[i], bfr[j], acc[i][j], 0, 0, 0);
    __syncthreads();
  }
  #pragma unroll
  for (int j = 0; j < 4; j++){
    int oc = o0 + o_off + j*16 + lm;
    #pragma unroll
    for (int i = 0; i < 4; i++){
      int rbase = n0 + m_off + i*16 + lk*4;
      #pragma unroll
      for (int r = 0; r < 4; r++)
        out[((size_t)b*kHW + rbase + r)*512 + oc] = f2b(acc[i][j][r]);
    }
  }
}

// per-channel sum/sumsq over bt (b,9216,512); grid (36, 8), 256 rows/block
__global__ __launch_bounds__(256) void k_stats(const bf16* __restrict__ bt,
                                               float* __restrict__ s1,
                                               float* __restrict__ s2){
  int n0 = blockIdx.x*256, b = blockIdx.y, t = threadIdx.x;
  __shared__ float l1[512];
  __shared__ float l2[512];
  for (int e = t; e < 512; e += 256){ l1[e] = 0.f; l2[e] = 0.f; }
  __syncthreads();
  int og = (t & 63)*8;
  int r0 = t >> 6;
  float a1[8] = {}, a2[8] = {};
  for (int r = r0; r < 256; r += 4){
    const bf16* p = bt + ((size_t)b*kHW + n0 + r)*512 + og;
    uint4 d = *(const uint4*)p;
    const unsigned short* us = (const unsigned short*)&d;
    #pragma unroll
    for (int j = 0; j < 8; j++){
      float v = __uint_as_float(((unsigned)us[j]) << 16);
      a1[j] += v; a2[j] += v*v;
    }
  }
  #pragma unroll
  for (int j = 0; j < 8; j++){
    atomicAdd(&l1[og + j], a1[j]);
    atomicAdd(&l2[og + j], a2[j]);
  }
  __syncthreads();
  for (int e = t; e < 512; e += 256){
    atomicAdd(&s1[e], l1[e]);
    atomicAdd(&s2[e], l2[e]);
  }
}

// ---------------------------------------------------------------------------
// q directly from low (NCHW fp32): q_t[b,x,h,32] bf16 ; grid (96 h, 8 b)
__global__ __launch_bounds__(256) void k_qlow(const float* __restrict__ low,
                                              const float* __restrict__ qq_w,
                                              const float* __restrict__ qq_b,
                                              bf16* __restrict__ q_t){
  int h = blockIdx.x, b = blockIdx.y, t = threadIdx.x;
  int tw = t % 32, to = t / 32;
  __shared__ __align__(16) float Al[64][98];
  __shared__ __align__(16) float Wl[64][36];
  float acc[3][4] = {};
  for (int c0 = 0; c0 < 512; c0 += 64){
    for (int e = t; e < 64*96; e += 256){
      int cl = e / 96, x = e % 96;
      Al[cl][x] = low[(((size_t)b*512 + c0 + cl)*96 + h)*96 + x];
    }
    for (int e = t; e < 32*64; e += 256){
      int o = e >> 6, k = e & 63;
      Wl[k][o] = qq_w[(size_t)o*512 + c0 + k];
    }
    __syncthreads();
    #pragma unroll 4
    for (int k = 0; k < 64; k++){
      float a_[3];
      #pragma unroll
      for (int i = 0; i < 3; i++) a_[i] = Al[k][tw*3 + i];
      float4 wv = *(const float4*)&Wl[k][to*4];
      float w_[4] = {wv.x, wv.y, wv.z, wv.w};
      #pragma unroll
      for (int i = 0; i < 3; i++)
        #pragma unroll
        for (int jj = 0; jj < 4; jj++) acc[i][jj] += a_[i]*w_[jj];
    }
    __syncthreads();
  }
  #pragma unroll
  for (int i = 0; i < 3; i++){
    int x = tw*3 + i;
    size_t base = (((size_t)b*96 + x)*96 + h)*32 + to*4;
    #pragma unroll
    for (int jj = 0; jj < 4; jj++) q_t[base + jj] = f2b(acc[i][jj] + qq_b[to*4 + jj]);
  }
}

// bf16-A (n,c) @ fp32-W (o,c)^T + fp32 bias -> bf16 (small-O path, used for k)
template<int BN, int OT>
__global__ __launch_bounds__(256) void k_gemm_bb(const bf16* __restrict__ A,
                                                 const float* __restrict__ Wt,
                                                 const float* __restrict__ bias,
                                                 bf16* __restrict__ out,
                                                 int Cin, int O){
  constexpr int TN = BN/4;
  int b = blockIdx.z, n0 = blockIdx.x*BN, o0 = blockIdx.y*OT, t = threadIdx.x;
  int tn = t % TN, to = t / TN;
  __shared__ __align__(16) float As[32][BN+4];
  __shared__ __align__(16) float Ws[32][OT+4];
  float acc[4][4] = {};
  const bf16* Ab = A + (size_t)b*kHW*Cin;
  for (int c0 = 0; c0 < Cin; c0 += 32){
    for (int e = t; e < BN*32; e += 256){
      int nl = e >> 5, kk = e & 31;
      As[kk][nl] = b2f(Ab[(size_t)(n0+nl)*Cin + c0 + kk]);
    }
    for (int e = t; e < OT*32; e += 256){
      int ol = e >> 5, kk = e & 31;
      Ws[kk][ol] = Wt[(size_t)(o0+ol)*Cin + c0 + kk];
    }
    __syncthreads();
    #pragma unroll
    for (int kk = 0; kk < 32; kk++){
      float4 av = *(const float4*)&As[kk][tn*4];
      float4 wv = *(const float4*)&Ws[kk][to*4];
      float a_[4] = {av.x, av.y, av.z, av.w};
      float w_[4] = {wv.x, wv.y, wv.z, wv.w};
      #pragma unroll
      for (int i = 0; i < 4; i++)
        #pragma unroll
        for (int jj = 0; jj < 4; jj++) acc[i][jj] += a_[i]*w_[jj];
    }
    __syncthreads();
  }
  #pragma unroll
  for (int i = 0; i < 4; i++){
    size_t base = ((size_t)b*kHW + n0 + tn*4 + i)*(size_t)O + o0 + to*4;
    #pragma unroll
    for (int jj = 0; jj < 4; jj++) out[base + jj] = f2b(acc[i][jj] + bias[o0 + to*4 + jj]);
  }
}

// ---------------------------------------------------------------------------
// eH: att[b,h,w,j] = sum_c q_t[b,w,h,c]*k_t[b,w,j,c]  (-1e9 if j==h); grid (96 w, 8 b)
__global__ __launch_bounds__(256) void k_eH(const bf16* __restrict__ q_t,
                                            const bf16* __restrict__ k_t,
                                            bf16* __restrict__ att){
  int w = blockIdx.x, b = blockIdx.y, t = threadIdx.x;
  __shared__ float Qs[96][33];
  __shared__ float Ks[96][33];
  const bf16* Qp = q_t + (((size_t)b*96 + w)*96)*32;
  const bf16* Kp = k_t + (((size_t)b*96 + w)*96)*32;
  for (int e = t; e < 3072; e += 256){ Qs[e>>5][e&31] = b2f(Qp[e]); Ks[e>>5][e&31] = b2f(Kp[e]); }
  __syncthreads();
  int tj = t % 16, th = t / 16;
  float acc[6][6] = {};
  #pragma unroll 4
  for (int c = 0; c < 32; c++){
    float qa[6], kb[6];
    #pragma unroll
    for (int i = 0; i < 6; i++) qa[i] = Qs[th*6 + i][c];
    #pragma unroll
    for (int jj = 0; jj < 6; jj++) kb[jj] = Ks[tj*6 + jj][c];
    #pragma unroll
    for (int i = 0; i < 6; i++)
      #pragma unroll
      for (int jj = 0; jj < 6; jj++) acc[i][jj] += qa[i]*kb[jj];
  }
  #pragma unroll
  for (int i = 0; i < 6; i++){
    int h = th*6 + i;
    size_t base = (((size_t)b*96 + h)*96 + w)*192;
    #pragma unroll
    for (int jj = 0; jj < 6; jj++){
      int jg = tj*6 + jj;
      float e = acc[i][jj];
      if (jg == h) e += -1000000000.0f;
      att[base + jg] = f2b(e);
    }
  }
}

// eW: att[b,h,w,96+j] = sum_c q_t[b,w,h,c]*k_t[b,j,h,c]; grid (96 h, 8 b)
__global__ __launch_bounds__(256) void k_eW(const bf16* __restrict__ q_t,
                                            const bf16* __restrict__ k_t,
                                            bf16* __restrict__ att){
  int h = blockIdx.x, b = blockIdx.y, t = threadIdx.x;
  __shared__ float Qs[96][33];
  __shared__ float Ks[96][33];
  for (int e = t; e < 3072; e += 256){
    int wl = e >> 5, c = e & 31;
    size_t idx = (((size_t)b*96 + wl)*96 + h)*32 + c;
    Qs[wl][c] = b2f(q_t[idx]);
    Ks[wl][c] = b2f(k_t[idx]);
  }
  __syncthreads();
  int tj = t % 16, tw = t / 16;
  float acc[6][6] = {};
  #pragma unroll 4
  for (int c = 0; c < 32; c++){
    float qa[6], kb[6];
    #pragma unroll
    for (int i = 0; i < 6; i++) qa[i] = Qs[tw*6 + i][c];
    #pragma unroll
    for (int jj = 0; jj < 6; jj++) kb[jj] = Ks[tj*6 + jj][c];
    #pragma unroll
    for (int i = 0; i < 6; i++)
      #pragma unroll
      for (int jj = 0; jj < 6; jj++) acc[i][jj] += qa[i]*kb[jj];
  }
  #pragma unroll
  for (int i = 0; i < 6; i++){
    int wl = tw*6 + i;
    size_t base = (((size_t)b*96 + h)*96 + wl)*192 + 96;
    #pragma unroll
    for (int jj = 0; jj < 6; jj++) att[base + tj*6 + jj] = f2b(acc[i][jj]);
  }
}

// softmax over 192, one wave per row; grid 18432
__global__ __launch_bounds__(256) void k_softmax(bf16* __restrict__ att){
  int t = threadIdx.x;
  int row = blockIdx.x*4 + (t >> 6);
  int lane = t & 63;
  size_t base = (size_t)row * 192;
  float x0 = b2f(att[base + lane]);
  float x1 = b2f(att[base + 64 + lane]);
  float x2 = b2f(att[base + 128 + lane]);
  float m = fmaxf(x0, fmaxf(x1, x2));
  #pragma unroll
  for (int off = 32; off; off >>= 1) m = fmaxf(m, __shfl_xor(m, off));
  float e0 = __expf(x0 - m), e1 = __expf(x1 - m), e2 = __expf(x2 - m);
  float s = e0 + e1 + e2;
  #pragma unroll
  for (int off = 32; off; off >>= 1) s += __shfl_xor(s, off);
  float inv = 1.0f / s;
  att[base + lane]       = f2b(e0 * inv);
  att[base + 64 + lane]  = f2b(e1 * inv);
  att[base + 128 + lane] = f2b(e2 * inv);
}

// outH: accb[b,w,h,c] = sum_j att[b,h,w,j]*v_t[b,w,j,c]; grid (96 w, 8 b, 2)
__global__ __launch_bounds__(256) void k_outH(const bf16* __restrict__ att,
                                              const bf16* __restrict__ v_t,
                                              bf16* __restrict__ accb){
  int w = blockIdx.x, b = blockIdx.y, c0 = blockIdx.z * 128, t = threadIdx.x;
  int tc = t % 16, th = t / 16;
  __shared__ float As[96][33];
  __shared__ __align__(16) float Vs[32][128];
  float acc[6][8] = {};
  for (int j0 = 0; j0 < 96; j0 += 32){
    for (int e = t; e < 3072; e += 256){
      int hh = e >> 5, jj = e & 31;
      As[hh][jj] = b2f(att[(((size_t)b*96 + hh)*96 + w)*192 + j0 + jj]);
    }
    for (int e = t; e < 4096; e += 256){
      int jj = e >> 7, c = e & 127;
      Vs[jj][c] = b2f(v_t[(((size_t)b*96 + w)*96 + j0 + jj)*256 + c0 + c]);
    }
    __syncthreads();
    #pragma unroll 2
    for (int jj = 0; jj < 32; jj++){
      float a_[6];
      #pragma unroll
      for (int i = 0; i < 6; i++) a_[i] = As[th*6 + i][jj];
      float4 v0 = *(const float4*)&Vs[jj][tc*4];
      float4 v1 = *(const float4*)&Vs[jj][64 + tc*4];
      #pragma unroll
      for (int i = 0; i < 6; i++){
        acc[i][0] += a_[i]*v0.x; acc[i][1] += a_[i]*v0.y;
        acc[i][2] += a_[i]*v0.z; acc[i][3] += a_[i]*v0.w;
        acc[i][4] += a_[i]*v1.x; acc[i][5] += a_[i]*v1.y;
        acc[i][6] += a_[i]*v1.z; acc[i][7] += a_[i]*v1.w;
      }
    }
    __syncthreads();
  }
  #pragma unroll
  for (int i = 0; i < 6; i++){
    int h = th*6 + i;
    size_t base = (((size_t)b*96 + w)*96 + h)*256 + c0;
    #pragma unroll
    for (int jj = 0; jj < 4; jj++) accb[base + tc*4 + jj]      = f2b(acc[i][jj]);
    #pragma unroll
    for (int jj = 0; jj < 4; jj++) accb[base + 64 + tc*4 + jj] = f2b(acc[i][4 + jj]);
  }
}

// outW + residual: vf_t[b,w,h,c] += g*(accb + sum_j att[...,96+j]*v_t[b,j,h,c]); grid (96 h, 8 b, 2)
__global__ __launch_bounds__(256) void k_outW(const bf16* __restrict__ att,
                                              const bf16* __restrict__ v_t,
                                              const bf16* __restrict__ accb,
                                              const float* __restrict__ gamma_p,
                                              bf16* __restrict__ vf_t){
  int h = blockIdx.x, b = blockIdx.y, c0 = blockIdx.z * 128, t = threadIdx.x;
  int tc = t % 16, tw = t / 16;
  __shared__ float As[96][33];
  __shared__ __align__(16) float Vs[32][128];
  float acc[6][8] = {};
  for (int j0 = 0; j0 < 96; j0 += 32){
    for (int e = t; e < 3072; e += 256){
      int wl = e >> 5, jj = e & 31;
      As[wl][jj] = b2f(att[(((size_t)b*96 + h)*96 + wl)*192 + 96 + j0 + jj]);
    }
    for (int e = t; e < 4096; e += 256){
      int jj = e >> 7, c = e & 127;
      Vs[jj][c] = b2f(v_t[(((size_t)b*96 + j0 + jj)*96 + h)*256 + c0 + c]);
    }
    __syncthreads();
    #pragma unroll 2
    for (int jj = 0; jj < 32; jj++){
      float a_[6];
      #pragma unroll
      for (int i = 0; i < 6; i++) a_[i] = As[tw*6 + i][jj];
      float4 v0 = *(const float4*)&Vs[jj][tc*4];
      float4 v1 = *(const float4*)&Vs[jj][64 + tc*4];
      #pragma unroll
      for (int i = 0; i < 6; i++){
        acc[i][0] += a_[i]*v0.x; acc[i][1] += a_[i]*v0.y;
        acc[i][2] += a_[i]*v0.z; acc[i][3] += a_[i]*v0.w;
        acc[i][4] += a_[i]*v1.x; acc[i][5] += a_[i]*v1.y;
        acc[i][6] += a_[i]*v1.z; acc[i][7] += a_[i]*v1.w;
      }
    }
    __syncthreads();
  }
  float g = gamma_p[0];
  #pragma unroll
  for (int i = 0; i < 6; i++){
    int wl = tw*6 + i;
    size_t base = (((size_t)b*96 + wl)*96 + h)*256 + c0;
    #pragma unroll
    for (int jj = 0; jj < 8; jj++){
      size_t idx = base + (jj >> 2)*64 + tc*4 + (jj & 3);
      vf_t[idx] = f2b(b2f(vf_t[idx]) + g*(acc[i][jj] + b2f(accb[idx])));
    }
  }
}

// ---------------------------------------------------------------------------
__global__ void k_bnprep(const float* __restrict__ s1, const float* __restrict__ s2,
                         const float* __restrict__ sc, const float* __restrict__ bi,
                         float2* __restrict__ ab){
  int co = blockIdx.x*256 + threadIdx.x;
  if (co >= 512) return;
  const float N = 73728.0f;
  float mean = s1[co] / N;
  float var  = s2[co] / N - mean*mean;
  if (var < 0.f) var = 0.f;
  float a = rsqrtf(var + 1e-5f) * sc[co];
  ab[co] = make_float2(a, bi[co] - mean*a);
}

// BN + relu + transpose (b,w,h,co) -> (b,co,h,w) fp32; grid (3, 96, 8)
__global__ __launch_bounds__(256) void k_bnout(const bf16* __restrict__ bt,
                                               const float2* __restrict__ ab,
                                               float* __restrict__ out){
  int w0 = blockIdx.x*32, h = blockIdx.y, b = blockIdx.z, t = threadIdx.x;
  __shared__ float Tl[32][33];
  for (int co0 = 0; co0 < 512; co0 += 32){
    for (int e = t; e < 1024; e += 256){
      int wl = e >> 5, co = e & 31;
      Tl[wl][co] = b2f(bt[(((size_t)b*96 + w0 + wl)*96 + h)*512 + co0 + co]);
    }
    __syncthreads();
    for (int e = t; e < 1024; e += 256){
      int co = e >> 5, wl = e & 31;
      float2 s = ab[co0 + co];
      float v = fmaxf(Tl[wl][co]*s.x + s.y, 0.0f);
      out[(((size_t)b*512 + co0 + co)*96 + h)*96 + w0 + wl] = v;
    }
    __syncthreads();
  }
}

// ---------------------------------------------------------------------------
extern "C" void kernel_launch(void* const* d_in, const int* in_sizes, int n_in,
                              void* d_out, int out_size, void* d_ws, size_t ws_size,
                              hipStream_t stream){
  (void)in_sizes; (void)n_in; (void)out_size; (void)ws_size;
  const float* low   = (const float*)d_in[0];
  const float* high  = (const float*)d_in[1];
  const float* c1w   = (const float*)d_in[2];
  const float* c1b   = (const float*)d_in[3];
  const float* c2w   = (const float*)d_in[4];
  const float* c2b   = (const float*)d_in[5];
  const float* qw    = (const float*)d_in[6];
  const float* qb    = (const float*)d_in[7];
  const float* kw    = (const float*)d_in[8];
  const float* kb    = (const float*)d_in[9];
  const float* vw    = (const float*)d_in[10];
  const float* vb    = (const float*)d_in[11];
  const float* gamma = (const float*)d_in[12];
  const float* bw    = (const float*)d_in[13];
  const float* bns   = (const float*)d_in[14];
  const float* bnb   = (const float*)d_in[15];
  float* out = (float*)d_out;

  char* wsb = (char*)d_ws;
  // workspace layout — total 223,027,328 bytes (~212.7 MB)
  bf16*   hf_t = (bf16*) (wsb + 0);            // 75,497,472  (b, x*96+y, 512)
  bf16*   vf_t = (bf16*) (wsb + 75497472);     // 37,748,736  (b, x*96+y, 256)
  bf16*   q_t  = (bf16*) (wsb + 113246208);    //  4,718,592
  float*  qq_w = (float*)(wsb + 117964800);    //     65,536
  float*  qq_b = (float*)(wsb + 118030336);    //        128
  float*  s1   = (float*)(wsb + 118030464);    //      2,048
  float*  s2   = (float*)(wsb + 118032512);    //      2,048
  float2* ab   = (float2*)(wsb + 118034560);   //      4,096
  bf16*   wbb  = (bf16*) (wsb + 118038656);    //    786,432  (bneck W bf16, 512x768)
  bf16*   wc2  = (bf16*) (wsb + 118825088);    //    262,144  (conv2 W bf16, 256x512)
  bf16*   wv   = (bf16*) (wsb + 119087232);    //    131,072  (v W bf16, 256x256)
  bf16*   v_t  = (bf16*) (wsb + 119218304);    // 37,748,736
  bf16*   att  = (bf16*) (wsb + 156967040);    // 28,311,552
  bf16*   accb = (bf16*) (wsb + 185278592);    // 37,748,736 -> ends 223,027,328
  bf16*   k_t  = (bf16*) (wsb + 185278592);    //  4,718,592 (aliases accb head; dead before accb written)
  bf16*   bt   = (bf16*) (wsb + 119218304);    // 75,497,472 (aliases v_t/att/accb-head; all dead at bneck)

  k_zero<<<4, 256, 0, stream>>>(s1);
  k_cvt<<<1536, 256, 0, stream>>>(bw,  wbb, 393216);
  k_cvt<<<512,  256, 0, stream>>>(c2w, wc2, 131072);
  k_cvt<<<256,  256, 0, stream>>>(vw,  wv,  65536);
  k_upsample<<<dim3(96, 8), 256, 0, stream>>>(high, hf_t);
  k_qqw<<<64, 256, 0, stream>>>(qw, c1w, qq_w);
  k_qqb<<<1, 64, 0, stream>>>(qw, c1b, qb, qq_b);
  k_mfma_gemm<<<dim3(72, 2, 8), 256, 0, stream>>>(hf_t, wc2, c2b, vf_t, 512, 256);
  k_qlow<<<dim3(96, 8), 256, 0, stream>>>(low, qq_w, qq_b, q_t);

  for (int r = 0; r < 2; r++){
    k_gemm_bb<128, 32><<<dim3(72, 1, 8), 256, 0, stream>>>(vf_t, kw, kb, k_t, 256, 32);
    k_mfma_gemm<<<dim3(72, 2, 8), 256, 0, stream>>>(vf_t, wv, vb, v_t, 256, 256);
    k_eH<<<dim3(96, 8), 256, 0, stream>>>(q_t, k_t, att);
    k_eW<<<dim3(96, 8), 256, 0, stream>>>(q_t, k_t, att);
    k_softmax<<<18432, 256, 0, stream>>>(att);
    k_outH<<<dim3(96, 8, 2), 256, 0, stream>>>(att, v_t, accb);
    k_outW<<<dim3(96, 8, 2), 256, 0, stream>>>(att, v_t, accb, gamma, vf_t);
  }

  k_bneck_mfma<<<dim3(72, 4, 8), 256, 0, stream>>>(vf_t, hf_t, wbb, bt);
  k_stats<<<dim3(36, 8), 256, 0, stream>>>(bt, s1, s2);
  k_bnprep<<<2, 256, 0, stream>>>(s1, s2, bns, bnb, ab);
  k_bnout<<<dim3(3, 96, 8), 256, 0, stream>>>(bt, ab, out);
}